// Round 13
// baseline (136.489 us; speedup 1.0000x reference)
//
#include <hip/hip_runtime.h>
#include <math.h>

#define T_STEPS 22
#define F_IN    12
#define HID     32

typedef __attribute__((ext_vector_type(8))) short  bf16x8;
typedef __attribute__((ext_vector_type(4)))  float f32x4;
typedef __attribute__((ext_vector_type(2)))  float f32x2;

union FragU { unsigned int u[4]; bf16x8 v; };

#define LOG2E    1.442695041f
#define TWOLOG2E 2.885390082f

static __device__ __forceinline__ unsigned short f2bf(float x) {
    unsigned int u = __builtin_bit_cast(unsigned int, x);
    return (unsigned short)((u + 0x7fffu + ((u >> 16) & 1u)) >> 16);
}

static __device__ __forceinline__ unsigned cvt_pk_bf16(float lo, float hi) {
    unsigned r;
    asm("v_cvt_pk_bf16_f32 %0, %1, %2" : "=v"(r) : "v"(lo), "v"(hi));
    return r;
}

static __device__ __forceinline__ float bf2f(short s_) {
    return __builtin_bit_cast(float, ((unsigned)(unsigned short)s_) << 16);
}

// 16x16x32 + chat column permutation (verified r8/r11): zero-shuffle h repack.
// ws layout (floats):
//   [0,2048)    wx16: [8 tile][64 lane] x 8 bf16, rows prescaled; k=12 = fused bias
//   [2048,4096) wh16: [8 tile][64 lane] x 8 bf16, cols chat-permuted, prescaled
//   [4096,4128) whd:  [4 s][8 j] f32; j<4 -> Whead[4s+j], j>=4 -> Whead[16+4s+j-4]
__global__ void prep_kernel(const float* __restrict__ Wih, const float* __restrict__ Whh,
                            const float* __restrict__ bih, const float* __restrict__ bhh,
                            const float* __restrict__ Whead, float* __restrict__ ws) {
    const int tid = threadIdx.x;  // 256
    unsigned short* wx = (unsigned short*)ws;
    unsigned short* wh = (unsigned short*)(ws + 2048);
    float* whd = ws + 4096;

    for (int e = tid; e < 512; e += 256) {
        int tile = e >> 6, lane = e & 63;
        int row = lane & 15, s = lane >> 4;
        int g = 16 * tile + row;
        float scale = (tile == 4 || tile == 5) ? TWOLOG2E : -LOG2E;  // g-gate: +2log2e
        for (int j = 0; j < 8; ++j) {
            int k = 8 * s + j;
            float v = 0.0f;
            if (k < F_IN)       v = Wih[g * F_IN + k];
            else if (k == F_IN) v = bih[g] + bhh[g];
            wx[e * 8 + j] = f2bf(scale * v);
            int cc = (j < 4) ? (4 * s + j) : (16 + 4 * s + (j - 4));  // chat(k)
            wh[e * 8 + j] = f2bf(scale * Whh[g * HID + cc]);
        }
    }
    if (tid < 32) {
        int s = tid >> 3, j = tid & 7;
        int orig = (j < 4) ? (4 * s + j) : (16 + 4 * s + (j - 8) + 4);
        // j>=4 -> 16+4s+(j-4)
        orig = (j < 4) ? (4 * s + j) : (16 + 4 * s + (j - 4));
        whd[tid] = Whead[orig];
    }
}

// DUAL-STREAM: each wave runs two independent 16-batch LSTM streams.
// S1's MFMA latency hides under S0's cell (separate pipes, in-order wave).
// (256,4) forces <=128 unified regs -> 4 waves/SIMD -> 8 streams/SIMD.
__global__ void __launch_bounds__(256, 4)
lstm_kernel(const float* __restrict__ x, const float* __restrict__ ws,
            const float* __restrict__ bheadp, float* __restrict__ out, int B) {
    const int tid  = threadIdx.x;
    const int lane = tid & 63;
    const int wave = tid >> 6;
    const int col  = lane & 15;
    const int s    = lane >> 4;
    const int base = blockIdx.x * 128 + wave * 32;
    int b0 = base + col;
    int b1 = base + 16 + col;
    const bool v0 = (b0 < B), v1 = (b1 < B);
    if (b0 >= B) b0 = B - 1;
    if (b1 >= B) b1 = B - 1;

    __shared__ float wlds[4096];    // 16 KB
#pragma unroll
    for (int i = 0; i < 4; ++i)
        ((float4*)wlds)[tid + i * 256] = ((const float4*)ws)[tid + i * 256];
    __syncthreads();

    const int off1 = (s == 0) ? 0 : 8;
    const int off2 = (s == 0) ? 4 : 8;
    const float* xa0 = x + (size_t)b0 * (T_STEPS * F_IN) + off1;
    const float* xb0 = x + (size_t)b0 * (T_STEPS * F_IN) + off2;
    const float* xa1 = x + (size_t)b1 * (T_STEPS * F_IN) + off1;
    const float* xb1 = x + (size_t)b1 * (T_STEPS * F_IN) + off2;

    f32x2 cA[4], cB[4];
#pragma unroll
    for (int q = 0; q < 4; ++q) { cA[q] = (f32x2){0.f, 0.f}; cB[q] = (f32x2){0.f, 0.f}; }
    bf16x8 hfA, hfB;
#pragma unroll
    for (int j = 0; j < 8; ++j) { hfA[j] = 0; hfB[j] = 0; }

    f32x4 zc;
#pragma unroll
    for (int q = 0; q < 4; ++q) zc[q] = 0.0f;

    const f32x2 one2 = {1.0f, 1.0f};

#pragma unroll 1
    for (int t = 0; t < T_STEPS; ++t) {
        // opaque zero: blocks LICM of weight ds_reads WITHOUT a memory clobber
        // (r7/r8/r11's "memory" clobber also killed x-load pipelining).
        int zr = 0;
        asm("" : "+v"(zr));
        const bf16x8* wx_l = ((const bf16x8*)wlds) + zr;          // [8][64]
        const bf16x8* wh_l = ((const bf16x8*)wlds) + 512 + zr;    // [8][64]

        float4 vaA = *(const float4*)(xa0 + t * F_IN);
        float4 vbA = *(const float4*)(xb0 + t * F_IN);
        float4 vaB = *(const float4*)(xa1 + t * F_IN);
        float4 vbB = *(const float4*)(xb1 + t * F_IN);

        FragU xfA, xfB;
        {
            unsigned p0 = cvt_pk_bf16(vaA.x, vaA.y);
            unsigned p1 = cvt_pk_bf16(vaA.z, vaA.w);
            unsigned p2 = cvt_pk_bf16(vbA.x, vbA.y);
            unsigned p3 = cvt_pk_bf16(vbA.z, vbA.w);
            if (s == 0)      { xfA.u[0] = p0; xfA.u[1] = p1; xfA.u[2] = p2;          xfA.u[3] = p3; }
            else if (s == 1) { xfA.u[0] = p0; xfA.u[1] = p1; xfA.u[2] = 0x00003f80u; xfA.u[3] = 0;  }
            else             { xfA.u[0] = 0;  xfA.u[1] = 0;  xfA.u[2] = 0;           xfA.u[3] = 0;  }
        }
        {
            unsigned p0 = cvt_pk_bf16(vaB.x, vaB.y);
            unsigned p1 = cvt_pk_bf16(vaB.z, vaB.w);
            unsigned p2 = cvt_pk_bf16(vbB.x, vbB.y);
            unsigned p3 = cvt_pk_bf16(vbB.z, vbB.w);
            if (s == 0)      { xfB.u[0] = p0; xfB.u[1] = p1; xfB.u[2] = p2;          xfB.u[3] = p3; }
            else if (s == 1) { xfB.u[0] = p0; xfB.u[1] = p1; xfB.u[2] = 0x00003f80u; xfB.u[3] = 0;  }
            else             { xfB.u[0] = 0;  xfB.u[1] = 0;  xfB.u[2] = 0;           xfB.u[3] = 0;  }
        }

        // ---- stream A MFMAs ----
        f32x4 aA0, aA1, aA2, aA3, aA4, aA5, aA6, aA7;
        aA0 = __builtin_amdgcn_mfma_f32_16x16x32_bf16(wx_l[0 * 64 + lane], xfA.v, zc, 0, 0, 0);
        aA1 = __builtin_amdgcn_mfma_f32_16x16x32_bf16(wx_l[1 * 64 + lane], xfA.v, zc, 0, 0, 0);
        aA2 = __builtin_amdgcn_mfma_f32_16x16x32_bf16(wx_l[2 * 64 + lane], xfA.v, zc, 0, 0, 0);
        aA3 = __builtin_amdgcn_mfma_f32_16x16x32_bf16(wx_l[3 * 64 + lane], xfA.v, zc, 0, 0, 0);
        aA4 = __builtin_amdgcn_mfma_f32_16x16x32_bf16(wx_l[4 * 64 + lane], xfA.v, zc, 0, 0, 0);
        aA5 = __builtin_amdgcn_mfma_f32_16x16x32_bf16(wx_l[5 * 64 + lane], xfA.v, zc, 0, 0, 0);
        aA6 = __builtin_amdgcn_mfma_f32_16x16x32_bf16(wx_l[6 * 64 + lane], xfA.v, zc, 0, 0, 0);
        aA7 = __builtin_amdgcn_mfma_f32_16x16x32_bf16(wx_l[7 * 64 + lane], xfA.v, zc, 0, 0, 0);
        aA0 = __builtin_amdgcn_mfma_f32_16x16x32_bf16(wh_l[0 * 64 + lane], hfA, aA0, 0, 0, 0);
        aA1 = __builtin_amdgcn_mfma_f32_16x16x32_bf16(wh_l[1 * 64 + lane], hfA, aA1, 0, 0, 0);
        aA2 = __builtin_amdgcn_mfma_f32_16x16x32_bf16(wh_l[2 * 64 + lane], hfA, aA2, 0, 0, 0);
        aA3 = __builtin_amdgcn_mfma_f32_16x16x32_bf16(wh_l[3 * 64 + lane], hfA, aA3, 0, 0, 0);
        aA4 = __builtin_amdgcn_mfma_f32_16x16x32_bf16(wh_l[4 * 64 + lane], hfA, aA4, 0, 0, 0);
        aA5 = __builtin_amdgcn_mfma_f32_16x16x32_bf16(wh_l[5 * 64 + lane], hfA, aA5, 0, 0, 0);
        aA6 = __builtin_amdgcn_mfma_f32_16x16x32_bf16(wh_l[6 * 64 + lane], hfA, aA6, 0, 0, 0);
        aA7 = __builtin_amdgcn_mfma_f32_16x16x32_bf16(wh_l[7 * 64 + lane], hfA, aA7, 0, 0, 0);

        // ---- stream B MFMAs (latency hides under stream A's cell below) ----
        f32x4 aB0, aB1, aB2, aB3, aB4, aB5, aB6, aB7;
        aB0 = __builtin_amdgcn_mfma_f32_16x16x32_bf16(wx_l[0 * 64 + lane], xfB.v, zc, 0, 0, 0);
        aB1 = __builtin_amdgcn_mfma_f32_16x16x32_bf16(wx_l[1 * 64 + lane], xfB.v, zc, 0, 0, 0);
        aB2 = __builtin_amdgcn_mfma_f32_16x16x32_bf16(wx_l[2 * 64 + lane], xfB.v, zc, 0, 0, 0);
        aB3 = __builtin_amdgcn_mfma_f32_16x16x32_bf16(wx_l[3 * 64 + lane], xfB.v, zc, 0, 0, 0);
        aB4 = __builtin_amdgcn_mfma_f32_16x16x32_bf16(wx_l[4 * 64 + lane], xfB.v, zc, 0, 0, 0);
        aB5 = __builtin_amdgcn_mfma_f32_16x16x32_bf16(wx_l[5 * 64 + lane], xfB.v, zc, 0, 0, 0);
        aB6 = __builtin_amdgcn_mfma_f32_16x16x32_bf16(wx_l[6 * 64 + lane], xfB.v, zc, 0, 0, 0);
        aB7 = __builtin_amdgcn_mfma_f32_16x16x32_bf16(wx_l[7 * 64 + lane], xfB.v, zc, 0, 0, 0);
        aB0 = __builtin_amdgcn_mfma_f32_16x16x32_bf16(wh_l[0 * 64 + lane], hfB, aB0, 0, 0, 0);
        aB1 = __builtin_amdgcn_mfma_f32_16x16x32_bf16(wh_l[1 * 64 + lane], hfB, aB1, 0, 0, 0);
        aB2 = __builtin_amdgcn_mfma_f32_16x16x32_bf16(wh_l[2 * 64 + lane], hfB, aB2, 0, 0, 0);
        aB3 = __builtin_amdgcn_mfma_f32_16x16x32_bf16(wh_l[3 * 64 + lane], hfB, aB3, 0, 0, 0);
        aB4 = __builtin_amdgcn_mfma_f32_16x16x32_bf16(wh_l[4 * 64 + lane], hfB, aB4, 0, 0, 0);
        aB5 = __builtin_amdgcn_mfma_f32_16x16x32_bf16(wh_l[5 * 64 + lane], hfB, aB5, 0, 0, 0);
        aB6 = __builtin_amdgcn_mfma_f32_16x16x32_bf16(wh_l[6 * 64 + lane], hfB, aB6, 0, 0, 0);
        aB7 = __builtin_amdgcn_mfma_f32_16x16x32_bf16(wh_l[7 * 64 + lane], hfB, aB7, 0, 0, 0);

        // ---- stream A cell (fused-rcp, 7 trans/unit, f32x2 packed) ----
        {
            f32x2 hv[4];
#pragma unroll
            for (int q = 0; q < 4; ++q) {
                f32x2 ei = {__builtin_amdgcn_exp2f(aA0[q]), __builtin_amdgcn_exp2f(aA1[q])};
                f32x2 ef = {__builtin_amdgcn_exp2f(aA2[q]), __builtin_amdgcn_exp2f(aA3[q])};
                f32x2 eg = {__builtin_amdgcn_exp2f(aA4[q]), __builtin_amdgcn_exp2f(aA5[q])};
                f32x2 eo = {__builtin_amdgcn_exp2f(aA6[q]), __builtin_amdgcn_exp2f(aA7[q])};
                f32x2 A  = (one2 + ei) * (one2 + eg);
                f32x2 F  = one2 + ef;
                f32x2 FA = F * A;
                f32x2 r1 = {__builtin_amdgcn_rcpf(FA.x), __builtin_amdgcn_rcpf(FA.y)};
                f32x2 t2 = eg * (f32x2){TWOLOG2E, TWOLOG2E} - (f32x2){TWOLOG2E, TWOLOG2E};
                f32x2 num = t2 * F + cA[q] * A;
                cA[q] = num * r1;
                f32x2 ec = {__builtin_amdgcn_exp2f(cA[q].x), __builtin_amdgcn_exp2f(cA[q].y)};
                f32x2 r2in = (one2 + eo) * (one2 + ec);
                f32x2 r2 = {__builtin_amdgcn_rcpf(r2in.x), __builtin_amdgcn_rcpf(r2in.y)};
                hv[q] = (ec - one2) * r2;
            }
            FragU hh;
            hh.u[0] = cvt_pk_bf16(hv[0].x, hv[1].x);
            hh.u[1] = cvt_pk_bf16(hv[2].x, hv[3].x);
            hh.u[2] = cvt_pk_bf16(hv[0].y, hv[1].y);
            hh.u[3] = cvt_pk_bf16(hv[2].y, hv[3].y);
            hfA = hh.v;
        }
        // ---- stream B cell ----
        {
            f32x2 hv[4];
#pragma unroll
            for (int q = 0; q < 4; ++q) {
                f32x2 ei = {__builtin_amdgcn_exp2f(aB0[q]), __builtin_amdgcn_exp2f(aB1[q])};
                f32x2 ef = {__builtin_amdgcn_exp2f(aB2[q]), __builtin_amdgcn_exp2f(aB3[q])};
                f32x2 eg = {__builtin_amdgcn_exp2f(aB4[q]), __builtin_amdgcn_exp2f(aB5[q])};
                f32x2 eo = {__builtin_amdgcn_exp2f(aB6[q]), __builtin_amdgcn_exp2f(aB7[q])};
                f32x2 A  = (one2 + ei) * (one2 + eg);
                f32x2 F  = one2 + ef;
                f32x2 FA = F * A;
                f32x2 r1 = {__builtin_amdgcn_rcpf(FA.x), __builtin_amdgcn_rcpf(FA.y)};
                f32x2 t2 = eg * (f32x2){TWOLOG2E, TWOLOG2E} - (f32x2){TWOLOG2E, TWOLOG2E};
                f32x2 num = t2 * F + cB[q] * A;
                cB[q] = num * r1;
                f32x2 ec = {__builtin_amdgcn_exp2f(cB[q].x), __builtin_amdgcn_exp2f(cB[q].y)};
                f32x2 r2in = (one2 + eo) * (one2 + ec);
                f32x2 r2 = {__builtin_amdgcn_rcpf(r2in.x), __builtin_amdgcn_rcpf(r2in.y)};
                hv[q] = (ec - one2) * r2;
            }
            FragU hh;
            hh.u[0] = cvt_pk_bf16(hv[0].x, hv[1].x);
            hh.u[1] = cvt_pk_bf16(hv[2].x, hv[3].x);
            hh.u[2] = cvt_pk_bf16(hv[0].y, hv[1].y);
            hh.u[3] = cvt_pk_bf16(hv[2].y, hv[3].y);
            hfB = hh.v;
        }
    }

    // head from bf16 h frags (r7-verified pattern): hf[e<4] = hv[e].x rows,
    // hf[e>=4] = hv[e-4].y rows -> matches whd[s][e] table order.
    const float* whd = ws + 4096 + s * 8;
    float y0 = 0.0f, y1 = 0.0f;
#pragma unroll
    for (int e = 0; e < 8; ++e) {
        y0 = fmaf(bf2f(hfA[e]), whd[e], y0);
        y1 = fmaf(bf2f(hfB[e]), whd[e], y1);
    }
    y0 += __shfl_xor(y0, 16, 64);
    y0 += __shfl_xor(y0, 32, 64);
    y1 += __shfl_xor(y1, 16, 64);
    y1 += __shfl_xor(y1, 32, 64);
    float bh = bheadp[0];
    y0 += bh;
    y1 += bh;
    float sp0 = fmaxf(y0, 0.0f) + log1pf(expf(-fabsf(y0)));
    float sp1 = fmaxf(y1, 0.0f) + log1pf(expf(-fabsf(y1)));
    if (v0 && s == 0) out[b0] = sp0;
    if (v1 && s == 0) out[b1] = sp1;
}

extern "C" void kernel_launch(void* const* d_in, const int* in_sizes, int n_in,
                              void* d_out, int out_size, void* d_ws, size_t ws_size,
                              hipStream_t stream) {
    const float* x     = (const float*)d_in[0];
    const float* Wih   = (const float*)d_in[1];
    const float* Whh   = (const float*)d_in[2];
    const float* bih   = (const float*)d_in[3];
    const float* bhh   = (const float*)d_in[4];
    const float* Whead = (const float*)d_in[5];
    const float* bhead = (const float*)d_in[6];
    float* out = (float*)d_out;
    float* ws  = (float*)d_ws;

    const int B = in_sizes[0] / (T_STEPS * F_IN);
    const int blocks = (B + 127) / 128;

    hipLaunchKernelGGL(prep_kernel, dim3(1), dim3(256), 0, stream,
                       Wih, Whh, bih, bhh, Whead, ws);
    hipLaunchKernelGGL(lstm_kernel, dim3(blocks), dim3(256), 0, stream,
                       x, ws, bhead, out, B);
}

// Round 14
// 99.039 us; speedup vs baseline: 1.3781x; 1.3781x over previous
//
#include <hip/hip_runtime.h>
#include <math.h>

#define T_STEPS 22
#define F_IN    12
#define HID     32

typedef __attribute__((ext_vector_type(8))) short  bf16x8;
typedef __attribute__((ext_vector_type(4)))  float f32x4;
typedef __attribute__((ext_vector_type(2)))  float f32x2;

union FragU { unsigned int u[4]; bf16x8 v; };

#define LOG2E    1.442695041f
#define TWOLOG2E 2.885390082f

static __device__ __forceinline__ unsigned short f2bf(float x) {
    unsigned int u = __builtin_bit_cast(unsigned int, x);
    return (unsigned short)((u + 0x7fffu + ((u >> 16) & 1u)) >> 16);
}

static __device__ __forceinline__ unsigned cvt_pk_bf16(float lo, float hi) {
    unsigned r;
    asm("v_cvt_pk_bf16_f32 %0, %1, %2" : "=v"(r) : "v"(lo), "v"(hi));
    return r;
}

static __device__ __forceinline__ float bf2f(short s_) {
    return __builtin_bit_cast(float, ((unsigned)(unsigned short)s_) << 16);
}

// 16x16x32 + chat column permutation (verified r8/r11/r13): zero-shuffle h repack.
// ws layout (floats):
//   [0,2048)    wx16: [8 tile][64 lane] x 8 bf16, rows prescaled; k=12 = fused bias
//   [2048,4096) wh16: [8 tile][64 lane] x 8 bf16, cols chat-permuted, prescaled
//   [4096,4128) whd:  [4 s][8 j] f32; j<4 -> Whead[4s+j], j>=4 -> Whead[16+4s+j-4]
__global__ void prep_kernel(const float* __restrict__ Wih, const float* __restrict__ Whh,
                            const float* __restrict__ bih, const float* __restrict__ bhh,
                            const float* __restrict__ Whead, float* __restrict__ ws) {
    const int tid = threadIdx.x;  // 256
    unsigned short* wx = (unsigned short*)ws;
    unsigned short* wh = (unsigned short*)(ws + 2048);
    float* whd = ws + 4096;

    for (int e = tid; e < 512; e += 256) {
        int tile = e >> 6, lane = e & 63;
        int row = lane & 15, s = lane >> 4;
        int g = 16 * tile + row;
        float scale = (tile == 4 || tile == 5) ? TWOLOG2E : -LOG2E;  // g-gate: +2log2e
        for (int j = 0; j < 8; ++j) {
            int k = 8 * s + j;
            float v = 0.0f;
            if (k < F_IN)       v = Wih[g * F_IN + k];
            else if (k == F_IN) v = bih[g] + bhh[g];
            wx[e * 8 + j] = f2bf(scale * v);
            int cc = (j < 4) ? (4 * s + j) : (16 + 4 * s + (j - 4));  // chat(k)
            wh[e * 8 + j] = f2bf(scale * Whh[g * HID + cc]);
        }
    }
    if (tid < 32) {
        int s = tid >> 3, j = tid & 7;
        int orig = (j < 4) ? (4 * s + j) : (16 + 4 * s + (j - 4));
        whd[tid] = Whead[orig];
    }
}

// DUAL-STREAM under (256,2): cap 256 unified regs (~154 needed -> NO forced
// spill, unlike r13's (256,4)=128 cap which spilled catastrophically).
// 2 waves/SIMD x 2 independent streams = 4 independent instruction streams
// per SIMD; stream B's stalls fill stream A's and vice versa.
__global__ void __launch_bounds__(256, 2)
lstm_kernel(const float* __restrict__ x, const float* __restrict__ ws,
            const float* __restrict__ bheadp, float* __restrict__ out, int B) {
    const int tid  = threadIdx.x;
    const int lane = tid & 63;
    const int wave = tid >> 6;
    const int col  = lane & 15;
    const int s    = lane >> 4;
    const int base = blockIdx.x * 128 + wave * 32;
    int b0 = base + col;
    int b1 = base + 16 + col;
    const bool v0 = (b0 < B), v1 = (b1 < B);
    if (b0 >= B) b0 = B - 1;
    if (b1 >= B) b1 = B - 1;

    __shared__ float wlds[4096];    // 16 KB
#pragma unroll
    for (int i = 0; i < 4; ++i)
        ((float4*)wlds)[tid + i * 256] = ((const float4*)ws)[tid + i * 256];
    __syncthreads();

    const int off1 = (s == 0) ? 0 : 8;
    const int off2 = (s == 0) ? 4 : 8;
    const float* xa0 = x + (size_t)b0 * (T_STEPS * F_IN) + off1;
    const float* xb0 = x + (size_t)b0 * (T_STEPS * F_IN) + off2;
    const float* xa1 = x + (size_t)b1 * (T_STEPS * F_IN) + off1;
    const float* xb1 = x + (size_t)b1 * (T_STEPS * F_IN) + off2;

    f32x2 cA[4], cB[4];
#pragma unroll
    for (int q = 0; q < 4; ++q) { cA[q] = (f32x2){0.f, 0.f}; cB[q] = (f32x2){0.f, 0.f}; }
    bf16x8 hfA, hfB;
#pragma unroll
    for (int j = 0; j < 8; ++j) { hfA[j] = 0; hfB[j] = 0; }

    f32x4 zc;
#pragma unroll
    for (int q = 0; q < 4; ++q) zc[q] = 0.0f;

    const f32x2 one2 = {1.0f, 1.0f};

#pragma unroll 1
    for (int t = 0; t < T_STEPS; ++t) {
        // opaque zero: blocks LICM of weight ds_reads WITHOUT a memory clobber
        int zr = 0;
        asm("" : "+v"(zr));
        const bf16x8* wx_l = ((const bf16x8*)wlds) + zr;          // [8][64]
        const bf16x8* wh_l = ((const bf16x8*)wlds) + 512 + zr;    // [8][64]

        float4 vaA = *(const float4*)(xa0 + t * F_IN);
        float4 vbA = *(const float4*)(xb0 + t * F_IN);
        float4 vaB = *(const float4*)(xa1 + t * F_IN);
        float4 vbB = *(const float4*)(xb1 + t * F_IN);

        FragU xfA, xfB;
        {
            unsigned p0 = cvt_pk_bf16(vaA.x, vaA.y);
            unsigned p1 = cvt_pk_bf16(vaA.z, vaA.w);
            unsigned p2 = cvt_pk_bf16(vbA.x, vbA.y);
            unsigned p3 = cvt_pk_bf16(vbA.z, vbA.w);
            if (s == 0)      { xfA.u[0] = p0; xfA.u[1] = p1; xfA.u[2] = p2;          xfA.u[3] = p3; }
            else if (s == 1) { xfA.u[0] = p0; xfA.u[1] = p1; xfA.u[2] = 0x00003f80u; xfA.u[3] = 0;  }
            else             { xfA.u[0] = 0;  xfA.u[1] = 0;  xfA.u[2] = 0;           xfA.u[3] = 0;  }
        }
        {
            unsigned p0 = cvt_pk_bf16(vaB.x, vaB.y);
            unsigned p1 = cvt_pk_bf16(vaB.z, vaB.w);
            unsigned p2 = cvt_pk_bf16(vbB.x, vbB.y);
            unsigned p3 = cvt_pk_bf16(vbB.z, vbB.w);
            if (s == 0)      { xfB.u[0] = p0; xfB.u[1] = p1; xfB.u[2] = p2;          xfB.u[3] = p3; }
            else if (s == 1) { xfB.u[0] = p0; xfB.u[1] = p1; xfB.u[2] = 0x00003f80u; xfB.u[3] = 0;  }
            else             { xfB.u[0] = 0;  xfB.u[1] = 0;  xfB.u[2] = 0;           xfB.u[3] = 0;  }
        }

        // ---- stream A MFMAs ----
        f32x4 aA0, aA1, aA2, aA3, aA4, aA5, aA6, aA7;
        aA0 = __builtin_amdgcn_mfma_f32_16x16x32_bf16(wx_l[0 * 64 + lane], xfA.v, zc, 0, 0, 0);
        aA1 = __builtin_amdgcn_mfma_f32_16x16x32_bf16(wx_l[1 * 64 + lane], xfA.v, zc, 0, 0, 0);
        aA2 = __builtin_amdgcn_mfma_f32_16x16x32_bf16(wx_l[2 * 64 + lane], xfA.v, zc, 0, 0, 0);
        aA3 = __builtin_amdgcn_mfma_f32_16x16x32_bf16(wx_l[3 * 64 + lane], xfA.v, zc, 0, 0, 0);
        aA4 = __builtin_amdgcn_mfma_f32_16x16x32_bf16(wx_l[4 * 64 + lane], xfA.v, zc, 0, 0, 0);
        aA5 = __builtin_amdgcn_mfma_f32_16x16x32_bf16(wx_l[5 * 64 + lane], xfA.v, zc, 0, 0, 0);
        aA6 = __builtin_amdgcn_mfma_f32_16x16x32_bf16(wx_l[6 * 64 + lane], xfA.v, zc, 0, 0, 0);
        aA7 = __builtin_amdgcn_mfma_f32_16x16x32_bf16(wx_l[7 * 64 + lane], xfA.v, zc, 0, 0, 0);
        aA0 = __builtin_amdgcn_mfma_f32_16x16x32_bf16(wh_l[0 * 64 + lane], hfA, aA0, 0, 0, 0);
        aA1 = __builtin_amdgcn_mfma_f32_16x16x32_bf16(wh_l[1 * 64 + lane], hfA, aA1, 0, 0, 0);
        aA2 = __builtin_amdgcn_mfma_f32_16x16x32_bf16(wh_l[2 * 64 + lane], hfA, aA2, 0, 0, 0);
        aA3 = __builtin_amdgcn_mfma_f32_16x16x32_bf16(wh_l[3 * 64 + lane], hfA, aA3, 0, 0, 0);
        aA4 = __builtin_amdgcn_mfma_f32_16x16x32_bf16(wh_l[4 * 64 + lane], hfA, aA4, 0, 0, 0);
        aA5 = __builtin_amdgcn_mfma_f32_16x16x32_bf16(wh_l[5 * 64 + lane], hfA, aA5, 0, 0, 0);
        aA6 = __builtin_amdgcn_mfma_f32_16x16x32_bf16(wh_l[6 * 64 + lane], hfA, aA6, 0, 0, 0);
        aA7 = __builtin_amdgcn_mfma_f32_16x16x32_bf16(wh_l[7 * 64 + lane], hfA, aA7, 0, 0, 0);

        // ---- stream B MFMAs ----
        f32x4 aB0, aB1, aB2, aB3, aB4, aB5, aB6, aB7;
        aB0 = __builtin_amdgcn_mfma_f32_16x16x32_bf16(wx_l[0 * 64 + lane], xfB.v, zc, 0, 0, 0);
        aB1 = __builtin_amdgcn_mfma_f32_16x16x32_bf16(wx_l[1 * 64 + lane], xfB.v, zc, 0, 0, 0);
        aB2 = __builtin_amdgcn_mfma_f32_16x16x32_bf16(wx_l[2 * 64 + lane], xfB.v, zc, 0, 0, 0);
        aB3 = __builtin_amdgcn_mfma_f32_16x16x32_bf16(wx_l[3 * 64 + lane], xfB.v, zc, 0, 0, 0);
        aB4 = __builtin_amdgcn_mfma_f32_16x16x32_bf16(wx_l[4 * 64 + lane], xfB.v, zc, 0, 0, 0);
        aB5 = __builtin_amdgcn_mfma_f32_16x16x32_bf16(wx_l[5 * 64 + lane], xfB.v, zc, 0, 0, 0);
        aB6 = __builtin_amdgcn_mfma_f32_16x16x32_bf16(wx_l[6 * 64 + lane], xfB.v, zc, 0, 0, 0);
        aB7 = __builtin_amdgcn_mfma_f32_16x16x32_bf16(wx_l[7 * 64 + lane], xfB.v, zc, 0, 0, 0);
        aB0 = __builtin_amdgcn_mfma_f32_16x16x32_bf16(wh_l[0 * 64 + lane], hfB, aB0, 0, 0, 0);
        aB1 = __builtin_amdgcn_mfma_f32_16x16x32_bf16(wh_l[1 * 64 + lane], hfB, aB1, 0, 0, 0);
        aB2 = __builtin_amdgcn_mfma_f32_16x16x32_bf16(wh_l[2 * 64 + lane], hfB, aB2, 0, 0, 0);
        aB3 = __builtin_amdgcn_mfma_f32_16x16x32_bf16(wh_l[3 * 64 + lane], hfB, aB3, 0, 0, 0);
        aB4 = __builtin_amdgcn_mfma_f32_16x16x32_bf16(wh_l[4 * 64 + lane], hfB, aB4, 0, 0, 0);
        aB5 = __builtin_amdgcn_mfma_f32_16x16x32_bf16(wh_l[5 * 64 + lane], hfB, aB5, 0, 0, 0);
        aB6 = __builtin_amdgcn_mfma_f32_16x16x32_bf16(wh_l[6 * 64 + lane], hfB, aB6, 0, 0, 0);
        aB7 = __builtin_amdgcn_mfma_f32_16x16x32_bf16(wh_l[7 * 64 + lane], hfB, aB7, 0, 0, 0);

        // ---- stream A cell (fused-rcp, 7 trans/unit, f32x2 packed) ----
        {
            f32x2 hv[4];
#pragma unroll
            for (int q = 0; q < 4; ++q) {
                f32x2 ei = {__builtin_amdgcn_exp2f(aA0[q]), __builtin_amdgcn_exp2f(aA1[q])};
                f32x2 ef = {__builtin_amdgcn_exp2f(aA2[q]), __builtin_amdgcn_exp2f(aA3[q])};
                f32x2 eg = {__builtin_amdgcn_exp2f(aA4[q]), __builtin_amdgcn_exp2f(aA5[q])};
                f32x2 eo = {__builtin_amdgcn_exp2f(aA6[q]), __builtin_amdgcn_exp2f(aA7[q])};
                f32x2 A  = (one2 + ei) * (one2 + eg);
                f32x2 F  = one2 + ef;
                f32x2 FA = F * A;
                f32x2 r1 = {__builtin_amdgcn_rcpf(FA.x), __builtin_amdgcn_rcpf(FA.y)};
                f32x2 t2 = eg * (f32x2){TWOLOG2E, TWOLOG2E} - (f32x2){TWOLOG2E, TWOLOG2E};
                f32x2 num = t2 * F + cA[q] * A;
                cA[q] = num * r1;
                f32x2 ec = {__builtin_amdgcn_exp2f(cA[q].x), __builtin_amdgcn_exp2f(cA[q].y)};
                f32x2 r2in = (one2 + eo) * (one2 + ec);
                f32x2 r2 = {__builtin_amdgcn_rcpf(r2in.x), __builtin_amdgcn_rcpf(r2in.y)};
                hv[q] = (ec - one2) * r2;
            }
            FragU hh;
            hh.u[0] = cvt_pk_bf16(hv[0].x, hv[1].x);
            hh.u[1] = cvt_pk_bf16(hv[2].x, hv[3].x);
            hh.u[2] = cvt_pk_bf16(hv[0].y, hv[1].y);
            hh.u[3] = cvt_pk_bf16(hv[2].y, hv[3].y);
            hfA = hh.v;
        }
        // ---- stream B cell ----
        {
            f32x2 hv[4];
#pragma unroll
            for (int q = 0; q < 4; ++q) {
                f32x2 ei = {__builtin_amdgcn_exp2f(aB0[q]), __builtin_amdgcn_exp2f(aB1[q])};
                f32x2 ef = {__builtin_amdgcn_exp2f(aB2[q]), __builtin_amdgcn_exp2f(aB3[q])};
                f32x2 eg = {__builtin_amdgcn_exp2f(aB4[q]), __builtin_amdgcn_exp2f(aB5[q])};
                f32x2 eo = {__builtin_amdgcn_exp2f(aB6[q]), __builtin_amdgcn_exp2f(aB7[q])};
                f32x2 A  = (one2 + ei) * (one2 + eg);
                f32x2 F  = one2 + ef;
                f32x2 FA = F * A;
                f32x2 r1 = {__builtin_amdgcn_rcpf(FA.x), __builtin_amdgcn_rcpf(FA.y)};
                f32x2 t2 = eg * (f32x2){TWOLOG2E, TWOLOG2E} - (f32x2){TWOLOG2E, TWOLOG2E};
                f32x2 num = t2 * F + cB[q] * A;
                cB[q] = num * r1;
                f32x2 ec = {__builtin_amdgcn_exp2f(cB[q].x), __builtin_amdgcn_exp2f(cB[q].y)};
                f32x2 r2in = (one2 + eo) * (one2 + ec);
                f32x2 r2 = {__builtin_amdgcn_rcpf(r2in.x), __builtin_amdgcn_rcpf(r2in.y)};
                hv[q] = (ec - one2) * r2;
            }
            FragU hh;
            hh.u[0] = cvt_pk_bf16(hv[0].x, hv[1].x);
            hh.u[1] = cvt_pk_bf16(hv[2].x, hv[3].x);
            hh.u[2] = cvt_pk_bf16(hv[0].y, hv[1].y);
            hh.u[3] = cvt_pk_bf16(hv[2].y, hv[3].y);
            hfB = hh.v;
        }
    }

    // head from bf16 h frags (verified r13): hf[e] order matches whd[s][e]
    const float* whd = ws + 4096 + s * 8;
    float y0 = 0.0f, y1 = 0.0f;
#pragma unroll
    for (int e = 0; e < 8; ++e) {
        y0 = fmaf(bf2f(hfA[e]), whd[e], y0);
        y1 = fmaf(bf2f(hfB[e]), whd[e], y1);
    }
    y0 += __shfl_xor(y0, 16, 64);
    y0 += __shfl_xor(y0, 32, 64);
    y1 += __shfl_xor(y1, 16, 64);
    y1 += __shfl_xor(y1, 32, 64);
    float bh = bheadp[0];
    y0 += bh;
    y1 += bh;
    float sp0 = fmaxf(y0, 0.0f) + log1pf(expf(-fabsf(y0)));
    float sp1 = fmaxf(y1, 0.0f) + log1pf(expf(-fabsf(y1)));
    if (v0 && s == 0) out[b0] = sp0;
    if (v1 && s == 0) out[b1] = sp1;
}

extern "C" void kernel_launch(void* const* d_in, const int* in_sizes, int n_in,
                              void* d_out, int out_size, void* d_ws, size_t ws_size,
                              hipStream_t stream) {
    const float* x     = (const float*)d_in[0];
    const float* Wih   = (const float*)d_in[1];
    const float* Whh   = (const float*)d_in[2];
    const float* bih   = (const float*)d_in[3];
    const float* bhh   = (const float*)d_in[4];
    const float* Whead = (const float*)d_in[5];
    const float* bhead = (const float*)d_in[6];
    float* out = (float*)d_out;
    float* ws  = (float*)d_ws;

    const int B = in_sizes[0] / (T_STEPS * F_IN);
    const int blocks = (B + 127) / 128;

    hipLaunchKernelGGL(prep_kernel, dim3(1), dim3(256), 0, stream,
                       Wih, Whh, bih, bhh, Whead, ws);
    hipLaunchKernelGGL(lstm_kernel, dim3(blocks), dim3(256), 0, stream,
                       x, ws, bhead, out, B);
}

// Round 15
// 88.143 us; speedup vs baseline: 1.5485x; 1.1236x over previous
//
#include <hip/hip_runtime.h>
#include <math.h>

#define T_STEPS 22
#define F_IN    12
#define HID     32

typedef __attribute__((ext_vector_type(8))) short  bf16x8;
typedef __attribute__((ext_vector_type(16))) float f32x16;
typedef __attribute__((ext_vector_type(2)))  float f32x2;

union FragU { unsigned int u[4]; bf16x8 v; };

#define LOG2E    1.442695041f
#define TWOLOG2E 2.885390082f

static __device__ __forceinline__ unsigned short f2bf(float x) {
    unsigned int u = __builtin_bit_cast(unsigned int, x);
    return (unsigned short)((u + 0x7fffu + ((u >> 16) & 1u)) >> 16);
}

static __device__ __forceinline__ unsigned cvt_pk_bf16(float lo, float hi) {
    unsigned r;
    asm("v_cvt_pk_bf16_f32 %0, %1, %2" : "=v"(r) : "v"(lo), "v"(hi));
    return r;
}

static __device__ __forceinline__ float bf2f(short s_) {
    return __builtin_bit_cast(float, ((unsigned)(unsigned short)s_) << 16);
}

// ws layout (floats):
//   [0,1024)    wx_frag: [4 m][64 lane] x 8 bf16, rows prescaled; k=12 = fused bias
//   [1024,3072) wh_frag: [4 m][2 kt][64 lane] x 8 bf16, rows prescaled
//   [3072,3104) whd: [2 hi][16 j] f32 in B-frag k-order (r6/r7 verified):
//               j<8 -> Whead[8*hi+j], j>=8 -> Whead[16+8*hi+(j-8)]
__global__ void prep_kernel(const float* __restrict__ Wih, const float* __restrict__ Whh,
                            const float* __restrict__ bih, const float* __restrict__ bhh,
                            const float* __restrict__ Whead, float* __restrict__ ws) {
    const int tid = threadIdx.x;  // 256
    unsigned short* wx = (unsigned short*)ws;
    unsigned short* wh = (unsigned short*)(ws + 1024);
    float* whd = ws + 3072;

    {   // wx: entry = m*64 + lane (== tid)
        int m = tid >> 6, lane = tid & 63;
        int g = 32 * m + (lane & 31);
        float scale = (m == 2) ? TWOLOG2E : -LOG2E;   // g-gate: +2log2e; i,f,o: -log2e
        int kbase = 8 * (lane >> 5);
        for (int j = 0; j < 8; ++j) {
            int k = kbase + j;
            float v = 0.0f;
            if (k < F_IN)       v = Wih[g * F_IN + k];
            else if (k == F_IN) v = bih[g] + bhh[g];
            wx[tid * 8 + j] = f2bf(scale * v);
        }
    }
    for (int e = tid; e < 4 * 2 * 64; e += 256) {
        int m = e >> 7, kt = (e >> 6) & 1, lane = e & 63;
        int g = 32 * m + (lane & 31);
        float scale = (m == 2) ? TWOLOG2E : -LOG2E;
        int kbase = 16 * kt + 8 * (lane >> 5);
        for (int j = 0; j < 8; ++j)
            wh[e * 8 + j] = f2bf(scale * Whh[g * HID + kbase + j]);
    }
    if (tid < 32) {
        int h2 = tid >> 4, j = tid & 15;
        int k = (j < 8) ? (8 * h2 + j) : (16 + 8 * h2 + (j - 8));
        whd[tid] = Whead[k];
    }
}

// r10 instruction stream with footprint <=128 unified regs:
//  - weight frags in LDS (opaque-zero blocks LICM; NO memory clobber so x
//    loads still pipeline) -> -48 VGPR
//  - h packed to bf16 inline; head reads hf frags -> -16 VGPR (no hv2)
//  - zc hoist + 1-step x prefetch
// Target: ~56 VGPR + 64 AGPR = 120 <= 128 -> 4 waves/SIMD (vs 2 at >128).
__global__ void __launch_bounds__(256, 2)
lstm_kernel(const float* __restrict__ x, const float* __restrict__ ws,
            const float* __restrict__ bheadp, float* __restrict__ out, int B) {
    const int tid  = threadIdx.x;
    const int lane = tid & 63;
    const int wave = tid >> 6;
    const int col  = lane & 31;
    const int hi   = lane >> 5;
    int b = blockIdx.x * 128 + wave * 32 + col;
    const bool valid = (b < B);
    if (b >= B) b = B - 1;          // clamp; all threads reach the barrier

    __shared__ float wlds[3072];    // 12 KB: wx [0,1024), wh [1024,3072)
#pragma unroll
    for (int i = 0; i < 3; ++i)
        ((float4*)wlds)[tid + i * 256] = ((const float4*)ws)[tid + i * 256];
    __syncthreads();

    // lo lanes read x[0..3],x[4..7]; hi lanes read x[8..11] (2nd load unused there)
    const float* xb1 = x + (size_t)b * (T_STEPS * F_IN) + (hi ? 8 : 0);
    const float* xb2 = x + (size_t)b * (T_STEPS * F_IN) + (hi ? 8 : 4);

    f32x2 c2[8];
#pragma unroll
    for (int p = 0; p < 8; ++p) c2[p] = (f32x2){0.f, 0.f};
    bf16x8 hf0, hf1;
#pragma unroll
    for (int j = 0; j < 8; ++j) { hf0[j] = 0; hf1[j] = 0; }

    f32x16 zc;   // hoisted zero C-in
#pragma unroll
    for (int q = 0; q < 16; ++q) zc[q] = 0.0f;

    const f32x2 one2 = {1.0f, 1.0f};

    float4 va = *(const float4*)(xb1);
    float4 vb = *(const float4*)(xb2);

#pragma unroll 1
    for (int t = 0; t < T_STEPS; ++t) {
        // opaque zero blocks LICM of the 12 weight ds_reads without a memory
        // clobber (r13/r14-proven: VGPR stays low, x loads still pipeline).
        int zr = 0;
        asm("" : "+v"(zr));
        const bf16x8* wx_l = ((const bf16x8*)wlds) + zr;          // [4][64]
        const bf16x8* wh_l = ((const bf16x8*)wlds) + 256 + zr;    // [4][2][64]

        // prefetch next step's x (consumed a full iteration later)
        const int tn = (t + 1 < T_STEPS) ? t + 1 : t;
        float4 na = *(const float4*)(xb1 + tn * F_IN);
        float4 nb = *(const float4*)(xb2 + tn * F_IN);

        FragU xf;
        xf.u[0] = cvt_pk_bf16(va.x, va.y);
        xf.u[1] = cvt_pk_bf16(va.z, va.w);
        unsigned w2 = cvt_pk_bf16(vb.x, vb.y);
        unsigned w3 = cvt_pk_bf16(vb.z, vb.w);
        xf.u[2] = hi ? 0x00003f80u : w2;   // k=12 -> 1.0 (fused bias feature)
        xf.u[3] = hi ? 0u : w3;

        f32x16 a0, a1, a2, a3;
        a0 = __builtin_amdgcn_mfma_f32_32x32x16_bf16(wx_l[0 * 64 + lane], xf.v, zc, 0, 0, 0);
        a1 = __builtin_amdgcn_mfma_f32_32x32x16_bf16(wx_l[1 * 64 + lane], xf.v, zc, 0, 0, 0);
        a2 = __builtin_amdgcn_mfma_f32_32x32x16_bf16(wx_l[2 * 64 + lane], xf.v, zc, 0, 0, 0);
        a3 = __builtin_amdgcn_mfma_f32_32x32x16_bf16(wx_l[3 * 64 + lane], xf.v, zc, 0, 0, 0);
        a0 = __builtin_amdgcn_mfma_f32_32x32x16_bf16(wh_l[(0 * 2 + 0) * 64 + lane], hf0, a0, 0, 0, 0);
        a1 = __builtin_amdgcn_mfma_f32_32x32x16_bf16(wh_l[(1 * 2 + 0) * 64 + lane], hf0, a1, 0, 0, 0);
        a2 = __builtin_amdgcn_mfma_f32_32x32x16_bf16(wh_l[(2 * 2 + 0) * 64 + lane], hf0, a2, 0, 0, 0);
        a3 = __builtin_amdgcn_mfma_f32_32x32x16_bf16(wh_l[(3 * 2 + 0) * 64 + lane], hf0, a3, 0, 0, 0);
        a0 = __builtin_amdgcn_mfma_f32_32x32x16_bf16(wh_l[(0 * 2 + 1) * 64 + lane], hf1, a0, 0, 0, 0);
        a1 = __builtin_amdgcn_mfma_f32_32x32x16_bf16(wh_l[(1 * 2 + 1) * 64 + lane], hf1, a1, 0, 0, 0);
        a2 = __builtin_amdgcn_mfma_f32_32x32x16_bf16(wh_l[(2 * 2 + 1) * 64 + lane], hf1, a2, 0, 0, 0);
        a3 = __builtin_amdgcn_mfma_f32_32x32x16_bf16(wh_l[(3 * 2 + 1) * 64 + lane], hf1, a3, 0, 0, 0);

        // Fused-rcp cell (7 trans/unit), f32x2-packed; h packed to bf16 inline.
        unsigned P[8];
#pragma unroll
        for (int p = 0; p < 8; ++p) {
            const int q0 = 2 * p, q1 = 2 * p + 1;
            f32x2 ei = {__builtin_amdgcn_exp2f(a0[q0]), __builtin_amdgcn_exp2f(a0[q1])};
            f32x2 ef = {__builtin_amdgcn_exp2f(a1[q0]), __builtin_amdgcn_exp2f(a1[q1])};
            f32x2 eg = {__builtin_amdgcn_exp2f(a2[q0]), __builtin_amdgcn_exp2f(a2[q1])};
            f32x2 eo = {__builtin_amdgcn_exp2f(a3[q0]), __builtin_amdgcn_exp2f(a3[q1])};
            f32x2 A  = (one2 + ei) * (one2 + eg);
            f32x2 F  = one2 + ef;
            f32x2 FA = F * A;
            f32x2 r1 = {__builtin_amdgcn_rcpf(FA.x), __builtin_amdgcn_rcpf(FA.y)};
            f32x2 t2 = eg * (f32x2){TWOLOG2E, TWOLOG2E} - (f32x2){TWOLOG2E, TWOLOG2E};
            f32x2 num = t2 * F + c2[p] * A;
            c2[p] = num * r1;
            f32x2 ec = {__builtin_amdgcn_exp2f(c2[p].x), __builtin_amdgcn_exp2f(c2[p].y)};
            f32x2 r2in = (one2 + eo) * (one2 + ec);
            f32x2 r2 = {__builtin_amdgcn_rcpf(r2in.x), __builtin_amdgcn_rcpf(r2in.y)};
            f32x2 hv = (ec - one2) * r2;
            P[p] = cvt_pk_bf16(hv.x, hv.y);
        }

        asm("v_permlane32_swap_b32 %0, %1" : "+v"(P[0]), "+v"(P[2]));
        asm("v_permlane32_swap_b32 %0, %1" : "+v"(P[1]), "+v"(P[3]));
        asm("v_permlane32_swap_b32 %0, %1" : "+v"(P[4]), "+v"(P[6]));
        asm("v_permlane32_swap_b32 %0, %1" : "+v"(P[5]), "+v"(P[7]));
        FragU h0; h0.u[0] = P[0]; h0.u[1] = P[1]; h0.u[2] = P[2]; h0.u[3] = P[3];
        FragU h1; h1.u[0] = P[4]; h1.u[1] = P[5]; h1.u[2] = P[6]; h1.u[3] = P[7];
        hf0 = h0.v;
        hf1 = h1.v;

        va = na; vb = nb;
    }

    // head from bf16 B-frags (r6/r7-verified): hf0[j]=h[8hi+j], hf1[j]=h[16+8hi+j]
    const float* whd = ws + 3072 + hi * 16;
    float y = 0.0f;
#pragma unroll
    for (int j = 0; j < 8; ++j) {
        y = fmaf(bf2f(hf0[j]), whd[j],     y);
        y = fmaf(bf2f(hf1[j]), whd[8 + j], y);
    }
    y += __shfl_xor(y, 32, 64);
    y += bheadp[0];
    float sp = fmaxf(y, 0.0f) + log1pf(expf(-fabsf(y)));
    if (valid && hi == 0) out[b] = sp;
}

extern "C" void kernel_launch(void* const* d_in, const int* in_sizes, int n_in,
                              void* d_out, int out_size, void* d_ws, size_t ws_size,
                              hipStream_t stream) {
    const float* x     = (const float*)d_in[0];
    const float* Wih   = (const float*)d_in[1];
    const float* Whh   = (const float*)d_in[2];
    const float* bih   = (const float*)d_in[3];
    const float* bhh   = (const float*)d_in[4];
    const float* Whead = (const float*)d_in[5];
    const float* bhead = (const float*)d_in[6];
    float* out = (float*)d_out;
    float* ws  = (float*)d_ws;

    const int B = in_sizes[0] / (T_STEPS * F_IN);
    const int blocks = (B + 127) / 128;

    hipLaunchKernelGGL(prep_kernel, dim3(1), dim3(256), 0, stream,
                       Wih, Whh, bih, bhh, Whead, ws);
    hipLaunchKernelGGL(lstm_kernel, dim3(blocks), dim3(256), 0, stream,
                       x, ws, bhead, out, B);
}